// Round 5
// baseline (1532.499 us; speedup 1.0000x reference)
//
#include <hip/hip_runtime.h>

#define B_ 2
#define N_ 2048
#define K_ 256
#define D_ 768
#define H_ 256
#define L_ 64
#define BK_ (B_*K_)

typedef __attribute__((ext_vector_type(8))) __bf16 bf16x8;
typedef __attribute__((ext_vector_type(8))) unsigned short ushort8;
typedef __attribute__((ext_vector_type(4))) unsigned short ushort4v;
typedef __attribute__((ext_vector_type(4))) float f32x4;

__device__ __forceinline__ float sigm(float x) { return 1.0f / (1.0f + __expf(-x)); }

// round-to-nearest-even fp32 -> bf16 (bit-twiddle; cold paths)
__device__ __forceinline__ unsigned short f2b(float f) {
    union { float f; unsigned int u; } v; v.f = f;
    unsigned int u = v.u;
    return (unsigned short)((u + 0x7FFFu + ((u >> 16) & 1u)) >> 16);
}
// hardware cvt (compiler emits v_cvt_pk_bf16_f32 for pairs; hot paths)
__device__ __forceinline__ unsigned short f2bc(float f) {
    __bf16 h = (__bf16)f;
    return __builtin_bit_cast(unsigned short, h);
}
__device__ __forceinline__ float b2f(unsigned short us) {
    union { unsigned int u; float f; } v; v.u = ((unsigned int)us) << 16;
    return v.f;
}
__device__ __forceinline__ bf16x8 ldb(const unsigned short* p) {
    ushort8 v = *(const ushort8*)p;
    return __builtin_bit_cast(bf16x8, v);
}
// load 8 fp32 -> bf16x8
__device__ __forceinline__ bf16x8 cvt8(const float* p) {
    float4 v0 = *(const float4*)p;
    float4 v1 = *(const float4*)(p + 4);
    ushort8 u;
    u[0] = f2b(v0.x); u[1] = f2b(v0.y); u[2] = f2b(v0.z); u[3] = f2b(v0.w);
    u[4] = f2b(v1.x); u[5] = f2b(v1.y); u[6] = f2b(v1.z); u[7] = f2b(v1.w);
    return __builtin_bit_cast(bf16x8, u);
}

// ---------- one-shot fp32->bf16 conversion of all static operands (incl. dist_emb) --
__global__ __launch_bounds__(256) void conv_all(
    const float* __restrict__ lw, const float* __restrict__ rw,
    const float* __restrict__ ow, const float* __restrict__ gw,
    const float* __restrict__ aw, const float* __restrict__ bw,
    const float* __restrict__ sv, const float* __restrict__ de,
    unsigned short* __restrict__ lwb, unsigned short* __restrict__ rwb,
    unsigned short* __restrict__ owb, unsigned short* __restrict__ gwb,
    unsigned short* __restrict__ wab, unsigned short* __restrict__ wbb,
    unsigned short* __restrict__ ub, unsigned short* __restrict__ deb)
{
    int i4 = (blockIdx.x * 256 + threadIdx.x) * 4;
    const float* src; unsigned short* dst; int off;
    if      (i4 <  196608) { src = lw; dst = lwb; off = 0; }
    else if (i4 <  393216) { src = rw; dst = rwb; off = 196608; }
    else if (i4 <  409600) { src = ow; dst = owb; off = 393216; }
    else if (i4 < 1589248) { src = gw; dst = gwb; off = 409600; }
    else if (i4 < 1638400) { src = aw; dst = wab; off = 1589248; }
    else if (i4 < 1687552) { src = bw; dst = wbb; off = 1638400; }
    else if (i4 < 2080768) { src = sv; dst = ub;  off = 1687552; }
    else if (i4 < 2097152) { src = de; dst = deb; off = 2080768; }
    else return;
    int j = i4 - off;
    float4 v = *(const float4*)&src[j];
    ushort4v p; p.x = f2b(v.x); p.y = f2b(v.y); p.z = f2b(v.z); p.w = f2b(v.w);
    *(ushort4v*)&dst[j] = p;
}

// ---------- left/right projections via MFMA (1 wave / 16x64 tile), both fp32 out ----
__global__ __launch_bounds__(64) void lr_mfma(
    const unsigned short* __restrict__ Ub,
    const unsigned short* __restrict__ lwb, const float* __restrict__ lb,
    const unsigned short* __restrict__ rwb, const float* __restrict__ rb,
    float* __restrict__ outL, float* __restrict__ outR)
{
    const int side = blockIdx.z;
    const unsigned short* __restrict__ W = side ? rwb : lwb;
    const float* __restrict__ bias = side ? rb : lb;
    float* __restrict__ outp = side ? outR : outL;
    const int r0 = blockIdx.x * 16, n0 = blockIdx.y * 64;
    const int lane = threadIdx.x;
    const int col = lane & 15, quad = lane >> 4;
    const unsigned short* arow = &Ub[(size_t)(r0 + col)*D_ + quad*8];
    f32x4 acc[4] = {};
    #pragma unroll 4
    for (int kc = 0; kc < D_; kc += 32) {
        bf16x8 a = ldb(arow + kc);
        #pragma unroll
        for (int nt = 0; nt < 4; ++nt) {
            bf16x8 bb = ldb(&W[(size_t)(n0 + nt*16 + col)*D_ + kc + quad*8]);
            acc[nt] = __builtin_amdgcn_mfma_f32_16x16x32_bf16(a, bb, acc[nt], 0, 0, 0);
        }
    }
    #pragma unroll
    for (int nt = 0; nt < 4; ++nt) {
        const int n = n0 + nt*16 + col;
        const float bv = bias[n];
        #pragma unroll
        for (int r = 0; r < 4; ++r) {
            const size_t idx = (size_t)(r0 + quad*4 + r)*H_ + n;
            outp[idx] = acc[nt][r] + bv;
        }
    }
}

// ---------- scores v9: LDS-resident dist-emb table (bf16, padded), k-outer ----------
// grid (K/64=4, K/8=32, B=2) = 256 blocks, 256 threads, 2 blocks/CU.
__global__ __launch_bounds__(256, 2) void scores_v9(
    const float* __restrict__ leftb, const float* __restrict__ rightb,
    const int* __restrict__ span_begin, const int* __restrict__ span_end,
    const unsigned short* __restrict__ deb, const unsigned short* __restrict__ owb,
    const float* __restrict__ out_b, const float* __restrict__ mask,
    float* __restrict__ S, unsigned short* __restrict__ Pt, int writeP)
{
    const int j0 = blockIdx.x * 64;
    const int i0 = blockIdx.y * 8;
    const int b  = blockIdx.z;
    const int tid = threadIdx.x;
    const int w = tid >> 6, lane = tid & 63, col = lane & 15, quad = lane >> 4;
    const int jrow = w*16 + col;

    __shared__ unsigned short sDe[64][272];  // full dist-emb table bf16, padded rows
    __shared__ float sL[8][256];             // left i-tile fp32
    __shared__ float sT[64][68];             // per-i transpose buffer
    __shared__ float sMask[8][64];
    __shared__ int   sBkt[8][64];

    // stage dist-emb table: 2048 ushort8 chunks
    #pragma unroll
    for (int q = 0; q < 8; ++q) {
        int c = tid + q*256;
        int row = c >> 5, seg = (c & 31) * 8;
        *(ushort8*)&sDe[row][seg] = *(const ushort8*)&deb[row*H_ + seg];
    }
    // buckets + mask (512 pairs)
    #pragma unroll
    for (int q = 0; q < 2; ++q) {
        int p = tid + q*256;
        int ii = p >> 6, jj = p & 63;
        int d = span_begin[b*K_ + j0 + jj] - span_end[b*K_ + i0 + ii];
        if (d < 0) d = -d;
        sBkt[ii][jj] = d > 63 ? 63 : d;
        sMask[ii][jj] = mask[(size_t)(b*K_ + i0 + ii)*K_ + j0 + jj];
    }
    // left tile: 512 float4s
    #pragma unroll
    for (int q = 0; q < 2; ++q) {
        int f = tid + q*256;
        int row = f >> 6, c4 = (f & 63) * 4;
        *(float4*)&sL[row][c4] = *(const float4*)&leftb[(size_t)(b*K_ + i0 + row)*H_ + c4];
    }
    __syncthreads();

    const unsigned short* sDeF = &sDe[0][0];
    int deoff[8];
    #pragma unroll
    for (int i = 0; i < 8; ++i) deoff[i] = sBkt[i][jrow] * 272;

    const float* rrow = &rightb[(size_t)(b*K_ + j0 + jrow)*H_ + quad*8];

    f32x4 acc[8][4] = {};
    #pragma unroll
    for (int k = 0; k < 8; ++k) {
        const float4 r0 = *(const float4*)&rrow[k*32];
        const float4 r1 = *(const float4*)&rrow[k*32 + 4];
        bf16x8 bbk[4];
        #pragma unroll
        for (int lt = 0; lt < 4; ++lt)
            bbk[lt] = ldb(&owb[(size_t)(lt*16 + col)*H_ + k*32 + quad*8]);
        #pragma unroll
        for (int i = 0; i < 8; ++i) {
            const ushort8 dv = *(const ushort8*)&sDeF[deoff[i] + k*32 + quad*8];
            const float* lr = &sL[i][k*32 + quad*8];
            const float4 l0 = *(const float4*)lr;
            const float4 l1 = *(const float4*)(lr + 4);
            bf16x8 a;
            a[0] = (__bf16)fmaxf(0.f, l0.x + r0.x + b2f(dv[0]));
            a[1] = (__bf16)fmaxf(0.f, l0.y + r0.y + b2f(dv[1]));
            a[2] = (__bf16)fmaxf(0.f, l0.z + r0.z + b2f(dv[2]));
            a[3] = (__bf16)fmaxf(0.f, l0.w + r0.w + b2f(dv[3]));
            a[4] = (__bf16)fmaxf(0.f, l1.x + r1.x + b2f(dv[4]));
            a[5] = (__bf16)fmaxf(0.f, l1.y + r1.y + b2f(dv[5]));
            a[6] = (__bf16)fmaxf(0.f, l1.z + r1.z + b2f(dv[6]));
            a[7] = (__bf16)fmaxf(0.f, l1.w + r1.w + b2f(dv[7]));
            #pragma unroll
            for (int lt = 0; lt < 4; ++lt)
                acc[i][lt] = __builtin_amdgcn_mfma_f32_16x16x32_bf16(a, bbk[lt], acc[i][lt], 0, 0, 0);
        }
    }

    float ob[4];
    #pragma unroll
    for (int lt = 0; lt < 4; ++lt) ob[lt] = out_b[lt*16 + col];

    #pragma unroll                      // keep acc[i] statically indexed (rule #20)
    for (int i = 0; i < 8; ++i) {
        __syncthreads();   // prior i's sT reads done
        #pragma unroll
        for (int lt = 0; lt < 4; ++lt)
            #pragma unroll
            for (int r = 0; r < 4; ++r)
                sT[w*16 + quad*4 + r][lt*16 + col] = acc[i][lt][r] + ob[lt];
        __syncthreads();
        const int jj = tid >> 2, seg = (tid & 3) * 16;
        const int j = j0 + jj, ii = i0 + i;
        if (writeP) {
            const float msk = sMask[i][jj];
            ushort8 o0, o1;
            #pragma unroll
            for (int e = 0; e < 8; ++e) {
                o0[e] = f2bc(sigm(sT[jj][seg + e]) * msk);
                o1[e] = f2bc(sigm(sT[jj][seg + 8 + e]) * msk);
            }
            unsigned short* dst = &Pt[(((size_t)b*K_ + j)*K_ + ii)*L_ + seg];
            *(ushort8*)&dst[0] = o0;
            *(ushort8*)&dst[8] = o1;
        } else {
            float* dst = &S[(((size_t)b*K_ + ii)*K_ + j)*L_ + seg];
            #pragma unroll
            for (int q2 = 0; q2 < 4; ++q2) {
                float4 v;
                v.x = sT[jj][seg + q2*4 + 0];
                v.y = sT[jj][seg + q2*4 + 1];
                v.z = sT[jj][seg + q2*4 + 2];
                v.w = sT[jj][seg + q2*4 + 3];
                *(float4*)&dst[q2*4] = v;
            }
        }
    }
}

// ---------- ctxt v5: 4-t phases, fragment-order LDS (conflict-free), 1 barrier/phase -
// grid 512 = 16 m x 8 t-blocks(32 t each, 8 phases of 4) x 2 modes x B; 512 threads.
// Phase schedule: write(regs->LDS buf[p&1]) -> barrier -> prefetch(p+1) -> compute(p).
// WAR on buf is ordered by the barrier (compute(p-2) precedes barrier(p-1) in all
// threads' program order, and write(p) follows barrier(p-1)).
// P staged in MFMA-fragment order: byte addr = tt*2048 + kc*1024 + lane*16, so the
// compute ds_read_b128 is linear in lane -> zero bank conflicts.
__global__ __launch_bounds__(512, 4) void ctxt_v5(
    const unsigned short* __restrict__ Pt, const float* __restrict__ U,
    const unsigned short* __restrict__ WAb, const unsigned short* __restrict__ WBb,
    const float* __restrict__ lens, float* __restrict__ cacc)
{
    const int bid = blockIdx.x;
    const int m0 = (bid & 15) << 4;
    const int t0 = ((bid >> 4) & 7) << 5;
    const int mode = (bid >> 7) & 1;
    const int b = bid >> 8;
    const unsigned short* __restrict__ Wb = mode ? WBb : WAb;
    const int tid = threadIdx.x;
    const int w = tid >> 6, lane = tid & 63, col = lane & 15, quad = lane >> 4;
    const int dbase = w * 96;

    __shared__ unsigned short sPf[2][4][1024];  // fragment-order P tiles
    __shared__ float sU[2][3072];               // 4 t-rows x 768

    // B fragments for this wave's 96-d slice: 48 VGPRs
    bf16x8 bw[6][2];
    #pragma unroll
    for (int dt = 0; dt < 6; ++dt)
        #pragma unroll
        for (int kc = 0; kc < 2; ++kc)
            bw[dt][kc] = ldb(&Wb[(size_t)(dbase + dt*16 + col)*L_ + kc*32 + quad*8]);

    // P stager coords: all 512 threads, one ushort8 each per phase
    const int ptt   = tid >> 7;              // 0..3 (tile within phase)
    const int pc    = tid & 127;
    const int prow  = pc & 15;               // m-row within tile
    const int pfrag = pc >> 4;               // 0..7
    const int pkc   = pfrag >> 2;
    const int pquad = pfrag & 3;
    const int pdst  = pkc*512 + (pquad*16 + prow)*8;   // ushort idx within [tt] tile
    const int pseg  = pfrag * 8;             // L-offset in source row
    size_t pRowBase, pTstep;
    if (mode) { pRowBase = ((size_t)(b*K_)*K_ + m0 + prow)*L_ + pseg;  pTstep = (size_t)K_*L_; }
    else      { pRowBase = ((size_t)(b*K_ + m0 + prow)*K_)*L_ + pseg;  pTstep = (size_t)L_; }

    // U stager coords: 768 float4s per phase; thread tid does f=tid, tid<256 also f=512+tid
    const int utt0 = tid / 192, uc0 = (tid % 192) * 4;
    const int uf1  = 512 + tid;
    const int utt1 = uf1 / 192, uc1 = (uf1 % 192) * 4;

    // prologue: load phase 0
    ushort8 pv = *(const ushort8*)&Pt[pRowBase + (size_t)(t0 + ptt)*pTstep];
    float4 uv0 = *(const float4*)&U[((size_t)b*K_ + t0 + utt0)*D_ + uc0];
    float4 uv1;
    if (tid < 256) uv1 = *(const float4*)&U[((size_t)b*K_ + t0 + utt1)*D_ + uc1];

    f32x4 acc[6] = {};
    for (int p = 0; p < 8; ++p) {
        const int cur = p & 1;
        // write staged regs to LDS
        *(ushort8*)&sPf[cur][ptt][pdst] = pv;
        *(float4*)&sU[cur][utt0*768 + uc0] = uv0;
        if (tid < 256) *(float4*)&sU[cur][utt1*768 + uc1] = uv1;
        __syncthreads();
        // prefetch next phase (latency hidden under compute below)
        if (p < 7) {
            const int tn = t0 + (p + 1)*4;
            pv  = *(const ushort8*)&Pt[pRowBase + (size_t)(tn + ptt)*pTstep];
            uv0 = *(const float4*)&U[((size_t)b*K_ + tn + utt0)*D_ + uc0];
            if (tid < 256) uv1 = *(const float4*)&U[((size_t)b*K_ + tn + utt1)*D_ + uc1];
        }
        // compute 4 t-tiles
        #pragma unroll
        for (int tt = 0; tt < 4; ++tt) {
            bf16x8 a0 = ldb(&sPf[cur][tt][lane*8]);
            bf16x8 a1 = ldb(&sPf[cur][tt][512 + lane*8]);
            #pragma unroll
            for (int dt = 0; dt < 6; ++dt) {
                f32x4 g = {0.f, 0.f, 0.f, 0.f};
                g = __builtin_amdgcn_mfma_f32_16x16x32_bf16(a0, bw[dt][0], g, 0, 0, 0);
                g = __builtin_amdgcn_mfma_f32_16x16x32_bf16(a1, bw[dt][1], g, 0, 0, 0);
                const float uu = sU[cur][tt*768 + dbase + dt*16 + col];
                acc[dt] += g * uu;
            }
        }
    }

    const float inv_len = 1.0f / lens[b];
    #pragma unroll
    for (int dt = 0; dt < 6; ++dt)
        #pragma unroll
        for (int r = 0; r < 4; ++r) {
            const int m = m0 + quad*4 + r;
            atomicAdd(&cacc[((size_t)(b*K_) + m)*D_ + dbase + dt*16 + col],
                      acc[dt][r] * inv_len);
        }
}

// ---------- gate via MFMA (1 wave / 16x64 tile), cconv fused ----------
__global__ __launch_bounds__(64) void gate_mfma(
    const unsigned short* __restrict__ Ub, const unsigned short* __restrict__ gwb,
    const float* __restrict__ gb,
    const float* __restrict__ Ucur, const float* __restrict__ Cc,
    float* __restrict__ Unext, unsigned short* __restrict__ Ubnext)
{
    const int r0 = blockIdx.x * 16, n0 = blockIdx.y * 64;
    const int lane = threadIdx.x;
    const int col = lane & 15, quad = lane >> 4;
    const unsigned short* arow_u = &Ub[(size_t)(r0 + col)*D_ + quad*8];
    const float* arow_c = &Cc[(size_t)(r0 + col)*D_ + quad*8];
    f32x4 acc[4] = {};
    #pragma unroll 4
    for (int kc = 0; kc < D_; kc += 32) {
        bf16x8 a = ldb(arow_u + kc);
        #pragma unroll
        for (int nt = 0; nt < 4; ++nt) {
            bf16x8 bb = ldb(&gwb[(size_t)(n0 + nt*16 + col)*(2*D_) + kc + quad*8]);
            acc[nt] = __builtin_amdgcn_mfma_f32_16x16x32_bf16(a, bb, acc[nt], 0, 0, 0);
        }
    }
    #pragma unroll 4
    for (int kc = 0; kc < D_; kc += 32) {
        bf16x8 a = cvt8(arow_c + kc);
        #pragma unroll
        for (int nt = 0; nt < 4; ++nt) {
            bf16x8 bb = ldb(&gwb[(size_t)(n0 + nt*16 + col)*(2*D_) + D_ + kc + quad*8]);
            acc[nt] = __builtin_amdgcn_mfma_f32_16x16x32_bf16(a, bb, acc[nt], 0, 0, 0);
        }
    }
    #pragma unroll
    for (int nt = 0; nt < 4; ++nt) {
        const int n = n0 + nt*16 + col;
        const float gbv = gb[n];
        #pragma unroll
        for (int r = 0; r < 4; ++r) {
            const size_t idx = (size_t)(r0 + quad*4 + r)*D_ + n;
            const float gg = sigm(acc[nt][r] + gbv);
            const float o = gg * Ucur[idx] + (1.f - gg) * Cc[idx];
            Unext[idx] = o;
            Ubnext[idx] = f2b(o);
        }
    }
}

// ---------- scatter updated rows into new_all ----------
__global__ __launch_bounds__(256) void scatter_kernel(
    const float* __restrict__ upd, const int* __restrict__ prune,
    const float* __restrict__ lens, float* __restrict__ out_all)
{
    const int blk = blockIdx.x;
    const int b = blk / K_, k = blk % K_;
    if ((float)k < lens[b]) {
        const int pi = prune[b*K_ + k];
        const int tid = threadIdx.x;
        if (tid < D_/4) {
            float4 v = *(const float4*)&upd[((size_t)b*K_ + k)*D_ + tid*4];
            *(float4*)&out_all[((size_t)b*N_ + pi)*D_ + tid*4] = v;
        }
    }
}

extern "C" void kernel_launch(void* const* d_in, const int* in_sizes, int n_in,
                              void* d_out, int out_size, void* d_ws, size_t ws_size,
                              hipStream_t stream) {
    (void)in_sizes; (void)n_in; (void)out_size; (void)ws_size;
    const float* all_span_vecs = (const float*)d_in[0];
    const float* span_vecs     = (const float*)d_in[1];
    const int*   span_begin    = (const int*)d_in[2];
    const int*   span_end      = (const int*)d_in[3];
    const float* mask          = (const float*)d_in[4];
    const float* lens          = (const float*)d_in[5];
    const int*   prune         = (const int*)d_in[6];
    const float* lw  = (const float*)d_in[7];
    const float* lb  = (const float*)d_in[8];
    const float* rw  = (const float*)d_in[9];
    const float* rb  = (const float*)d_in[10];
    const float* dist_emb = (const float*)d_in[11];
    const float* out_w    = (const float*)d_in[12];
    const float* out_b    = (const float*)d_in[13];
    const float* A_w = (const float*)d_in[14];
    const float* B_w = (const float*)d_in[15];
    const float* gw  = (const float*)d_in[16];
    const float* gb  = (const float*)d_in[17];

    float* out_all = (float*)d_out;
    float* out_upd = out_all + (size_t)B_*N_*D_;
    float* out_sc  = out_upd + (size_t)BK_*D_;

    float* ws     = (float*)d_ws;
    float* leftb  = ws;                            // BK*H fp32
    float* rightf = leftb + (size_t)BK_*H_;        // BK*H fp32 (right proj)
    float* U0     = rightf + (size_t)BK_*H_;       // BK*D
    float* U1     = U0 + (size_t)BK_*D_;           // BK*D
    float* cbuf   = U1 + (size_t)BK_*D_;           // BK*D
    unsigned short* WAb = (unsigned short*)(cbuf + (size_t)BK_*D_);
    unsigned short* WBb = WAb + (size_t)D_*L_;
    unsigned short* lwb = WBb + (size_t)D_*L_;
    unsigned short* rwb = lwb + (size_t)H_*D_;
    unsigned short* owb = rwb + (size_t)H_*D_;
    unsigned short* gwb = owb + (size_t)L_*H_;
    unsigned short* deb = gwb + (size_t)D_*2*D_;   // 64*H bf16
    unsigned short* Ub0 = deb + (size_t)64*H_;
    unsigned short* Ub1 = Ub0 + (size_t)BK_*D_;
    unsigned short* Pt  = Ub1 + (size_t)BK_*D_;    // B*K*K*L bf16

    hipMemcpyAsync(out_all, all_span_vecs, sizeof(float)*(size_t)B_*N_*D_,
                   hipMemcpyDeviceToDevice, stream);

    dim3 blk256(256), blk64(64), blk512(512);
    conv_all<<<dim3(2048), blk256, 0, stream>>>(lw, rw, out_w, gw, A_w, B_w, span_vecs, dist_emb,
                                                lwb, rwb, owb, gwb, WAb, WBb, Ub0, deb);
    lr_mfma<<<dim3(BK_/16, H_/64, 2), blk64, 0, stream>>>(Ub0, lwb, lb, rwb, rb, leftb, rightf);
    scores_v9<<<dim3(K_/64, K_/8, B_), blk256, 0, stream>>>(leftb, rightf, span_begin, span_end,
                                                            deb, owb, out_b, mask,
                                                            out_sc, Pt, 1);
    const float* Ucur = span_vecs;
    const unsigned short* Ubcur = Ub0;
    float* nexts[3] = {U0, U1, out_upd};
    unsigned short* nextsUb[3] = {Ub1, Ub0, Ub1};
    for (int it = 0; it < 3; ++it) {
        hipMemsetAsync(cbuf, 0, sizeof(float)*(size_t)BK_*D_, stream);
        ctxt_v5<<<dim3(512), blk512, 0, stream>>>(Pt, Ucur, WAb, WBb, lens, cbuf);
        gate_mfma<<<dim3(BK_/16, D_/64), blk64, 0, stream>>>(Ubcur, gwb, gb,
                                                             Ucur, cbuf, nexts[it], nextsUb[it]);
        Ucur = nexts[it];
        Ubcur = nextsUb[it];
        lr_mfma<<<dim3(BK_/16, H_/64, 2), blk64, 0, stream>>>(Ubcur, lwb, lb, rwb, rb, leftb, rightf);
        scores_v9<<<dim3(K_/64, K_/8, B_), blk256, 0, stream>>>(leftb, rightf, span_begin, span_end,
                                                                deb, owb, out_b, mask,
                                                                out_sc, Pt, it == 2 ? 0 : 1);
    }
    scatter_kernel<<<dim3(BK_), blk256, 0, stream>>>(out_upd, prune, lens, out_all);
}

// Round 6
// 439.366 us; speedup vs baseline: 3.4880x; 3.4880x over previous
//
#include <hip/hip_runtime.h>

#define B_ 2
#define N_ 2048
#define K_ 256
#define D_ 768
#define H_ 256
#define L_ 64
#define BK_ (B_*K_)

typedef __attribute__((ext_vector_type(8))) __bf16 bf16x8;
typedef __attribute__((ext_vector_type(8))) unsigned short ushort8;
typedef __attribute__((ext_vector_type(4))) unsigned short ushort4v;
typedef __attribute__((ext_vector_type(4))) float f32x4;

__device__ __forceinline__ float sigm(float x) { return 1.0f / (1.0f + __expf(-x)); }

// round-to-nearest-even fp32 -> bf16 (bit-twiddle; cold paths)
__device__ __forceinline__ unsigned short f2b(float f) {
    union { float f; unsigned int u; } v; v.f = f;
    unsigned int u = v.u;
    return (unsigned short)((u + 0x7FFFu + ((u >> 16) & 1u)) >> 16);
}
// hardware cvt (compiler emits v_cvt_pk_bf16_f32 for pairs; hot paths)
__device__ __forceinline__ unsigned short f2bc(float f) {
    __bf16 h = (__bf16)f;
    return __builtin_bit_cast(unsigned short, h);
}
__device__ __forceinline__ float b2f(unsigned short us) {
    union { unsigned int u; float f; } v; v.u = ((unsigned int)us) << 16;
    return v.f;
}
__device__ __forceinline__ bf16x8 ldb(const unsigned short* p) {
    ushort8 v = *(const ushort8*)p;
    return __builtin_bit_cast(bf16x8, v);
}
// load 8 fp32 -> bf16x8
__device__ __forceinline__ bf16x8 cvt8(const float* p) {
    float4 v0 = *(const float4*)p;
    float4 v1 = *(const float4*)(p + 4);
    ushort8 u;
    u[0] = f2b(v0.x); u[1] = f2b(v0.y); u[2] = f2b(v0.z); u[3] = f2b(v0.w);
    u[4] = f2b(v1.x); u[5] = f2b(v1.y); u[6] = f2b(v1.z); u[7] = f2b(v1.w);
    return __builtin_bit_cast(bf16x8, u);
}

// ---------- one-shot fp32->bf16 conversion of all static operands (incl. dist_emb) --
__global__ __launch_bounds__(256) void conv_all(
    const float* __restrict__ lw, const float* __restrict__ rw,
    const float* __restrict__ ow, const float* __restrict__ gw,
    const float* __restrict__ aw, const float* __restrict__ bw,
    const float* __restrict__ sv, const float* __restrict__ de,
    unsigned short* __restrict__ lwb, unsigned short* __restrict__ rwb,
    unsigned short* __restrict__ owb, unsigned short* __restrict__ gwb,
    unsigned short* __restrict__ wab, unsigned short* __restrict__ wbb,
    unsigned short* __restrict__ ub, unsigned short* __restrict__ deb)
{
    int i4 = (blockIdx.x * 256 + threadIdx.x) * 4;
    const float* src; unsigned short* dst; int off;
    if      (i4 <  196608) { src = lw; dst = lwb; off = 0; }
    else if (i4 <  393216) { src = rw; dst = rwb; off = 196608; }
    else if (i4 <  409600) { src = ow; dst = owb; off = 393216; }
    else if (i4 < 1589248) { src = gw; dst = gwb; off = 409600; }
    else if (i4 < 1638400) { src = aw; dst = wab; off = 1589248; }
    else if (i4 < 1687552) { src = bw; dst = wbb; off = 1638400; }
    else if (i4 < 2080768) { src = sv; dst = ub;  off = 1687552; }
    else if (i4 < 2097152) { src = de; dst = deb; off = 2080768; }
    else return;
    int j = i4 - off;
    float4 v = *(const float4*)&src[j];
    ushort4v p; p.x = f2b(v.x); p.y = f2b(v.y); p.z = f2b(v.z); p.w = f2b(v.w);
    *(ushort4v*)&dst[j] = p;
}

// ---------- left/right projections via MFMA (1 wave / 16x64 tile), both fp32 out ----
__global__ __launch_bounds__(64) void lr_mfma(
    const unsigned short* __restrict__ Ub,
    const unsigned short* __restrict__ lwb, const float* __restrict__ lb,
    const unsigned short* __restrict__ rwb, const float* __restrict__ rb,
    float* __restrict__ outL, float* __restrict__ outR)
{
    const int side = blockIdx.z;
    const unsigned short* __restrict__ W = side ? rwb : lwb;
    const float* __restrict__ bias = side ? rb : lb;
    float* __restrict__ outp = side ? outR : outL;
    const int r0 = blockIdx.x * 16, n0 = blockIdx.y * 64;
    const int lane = threadIdx.x;
    const int col = lane & 15, quad = lane >> 4;
    const unsigned short* arow = &Ub[(size_t)(r0 + col)*D_ + quad*8];
    f32x4 acc[4] = {};
    #pragma unroll 4
    for (int kc = 0; kc < D_; kc += 32) {
        bf16x8 a = ldb(arow + kc);
        #pragma unroll
        for (int nt = 0; nt < 4; ++nt) {
            bf16x8 bb = ldb(&W[(size_t)(n0 + nt*16 + col)*D_ + kc + quad*8]);
            acc[nt] = __builtin_amdgcn_mfma_f32_16x16x32_bf16(a, bb, acc[nt], 0, 0, 0);
        }
    }
    #pragma unroll
    for (int nt = 0; nt < 4; ++nt) {
        const int n = n0 + nt*16 + col;
        const float bv = bias[n];
        #pragma unroll
        for (int r = 0; r < 4; ++r) {
            const size_t idx = (size_t)(r0 + quad*4 + r)*H_ + n;
            outp[idx] = acc[nt][r] + bv;
        }
    }
}

// ---------- scores v9: LDS-resident dist-emb table (bf16, padded), k-outer ----------
// grid (K/64=4, K/8=32, B=2) = 256 blocks, 256 threads, 2 blocks/CU.
__global__ __launch_bounds__(256, 2) void scores_v9(
    const float* __restrict__ leftb, const float* __restrict__ rightb,
    const int* __restrict__ span_begin, const int* __restrict__ span_end,
    const unsigned short* __restrict__ deb, const unsigned short* __restrict__ owb,
    const float* __restrict__ out_b, const float* __restrict__ mask,
    float* __restrict__ S, unsigned short* __restrict__ Pt, int writeP)
{
    const int j0 = blockIdx.x * 64;
    const int i0 = blockIdx.y * 8;
    const int b  = blockIdx.z;
    const int tid = threadIdx.x;
    const int w = tid >> 6, lane = tid & 63, col = lane & 15, quad = lane >> 4;
    const int jrow = w*16 + col;

    __shared__ unsigned short sDe[64][272];  // full dist-emb table bf16, padded rows
    __shared__ float sL[8][256];             // left i-tile fp32
    __shared__ float sT[64][68];             // per-i transpose buffer
    __shared__ float sMask[8][64];
    __shared__ int   sBkt[8][64];

    // stage dist-emb table: 2048 ushort8 chunks
    #pragma unroll
    for (int q = 0; q < 8; ++q) {
        int c = tid + q*256;
        int row = c >> 5, seg = (c & 31) * 8;
        *(ushort8*)&sDe[row][seg] = *(const ushort8*)&deb[row*H_ + seg];
    }
    // buckets + mask (512 pairs)
    #pragma unroll
    for (int q = 0; q < 2; ++q) {
        int p = tid + q*256;
        int ii = p >> 6, jj = p & 63;
        int d = span_begin[b*K_ + j0 + jj] - span_end[b*K_ + i0 + ii];
        if (d < 0) d = -d;
        sBkt[ii][jj] = d > 63 ? 63 : d;
        sMask[ii][jj] = mask[(size_t)(b*K_ + i0 + ii)*K_ + j0 + jj];
    }
    // left tile: 512 float4s
    #pragma unroll
    for (int q = 0; q < 2; ++q) {
        int f = tid + q*256;
        int row = f >> 6, c4 = (f & 63) * 4;
        *(float4*)&sL[row][c4] = *(const float4*)&leftb[(size_t)(b*K_ + i0 + row)*H_ + c4];
    }
    __syncthreads();

    const unsigned short* sDeF = &sDe[0][0];
    int deoff[8];
    #pragma unroll
    for (int i = 0; i < 8; ++i) deoff[i] = sBkt[i][jrow] * 272;

    const float* rrow = &rightb[(size_t)(b*K_ + j0 + jrow)*H_ + quad*8];

    f32x4 acc[8][4] = {};
    #pragma unroll
    for (int k = 0; k < 8; ++k) {
        const float4 r0 = *(const float4*)&rrow[k*32];
        const float4 r1 = *(const float4*)&rrow[k*32 + 4];
        bf16x8 bbk[4];
        #pragma unroll
        for (int lt = 0; lt < 4; ++lt)
            bbk[lt] = ldb(&owb[(size_t)(lt*16 + col)*H_ + k*32 + quad*8]);
        #pragma unroll
        for (int i = 0; i < 8; ++i) {
            const ushort8 dv = *(const ushort8*)&sDeF[deoff[i] + k*32 + quad*8];
            const float* lr = &sL[i][k*32 + quad*8];
            const float4 l0 = *(const float4*)lr;
            const float4 l1 = *(const float4*)(lr + 4);
            bf16x8 a;
            a[0] = (__bf16)fmaxf(0.f, l0.x + r0.x + b2f(dv[0]));
            a[1] = (__bf16)fmaxf(0.f, l0.y + r0.y + b2f(dv[1]));
            a[2] = (__bf16)fmaxf(0.f, l0.z + r0.z + b2f(dv[2]));
            a[3] = (__bf16)fmaxf(0.f, l0.w + r0.w + b2f(dv[3]));
            a[4] = (__bf16)fmaxf(0.f, l1.x + r1.x + b2f(dv[4]));
            a[5] = (__bf16)fmaxf(0.f, l1.y + r1.y + b2f(dv[5]));
            a[6] = (__bf16)fmaxf(0.f, l1.z + r1.z + b2f(dv[6]));
            a[7] = (__bf16)fmaxf(0.f, l1.w + r1.w + b2f(dv[7]));
            #pragma unroll
            for (int lt = 0; lt < 4; ++lt)
                acc[i][lt] = __builtin_amdgcn_mfma_f32_16x16x32_bf16(a, bbk[lt], acc[i][lt], 0, 0, 0);
        }
    }

    float ob[4];
    #pragma unroll
    for (int lt = 0; lt < 4; ++lt) ob[lt] = out_b[lt*16 + col];

    #pragma unroll                      // keep acc[i] statically indexed (rule #20)
    for (int i = 0; i < 8; ++i) {
        __syncthreads();   // prior i's sT reads done
        #pragma unroll
        for (int lt = 0; lt < 4; ++lt)
            #pragma unroll
            for (int r = 0; r < 4; ++r)
                sT[w*16 + quad*4 + r][lt*16 + col] = acc[i][lt][r] + ob[lt];
        __syncthreads();
        const int jj = tid >> 2, seg = (tid & 3) * 16;
        const int j = j0 + jj, ii = i0 + i;
        if (writeP) {
            const float msk = sMask[i][jj];
            ushort8 o0, o1;
            #pragma unroll
            for (int e = 0; e < 8; ++e) {
                o0[e] = f2bc(sigm(sT[jj][seg + e]) * msk);
                o1[e] = f2bc(sigm(sT[jj][seg + 8 + e]) * msk);
            }
            unsigned short* dst = &Pt[(((size_t)b*K_ + j)*K_ + ii)*L_ + seg];
            *(ushort8*)&dst[0] = o0;
            *(ushort8*)&dst[8] = o1;
        } else {
            float* dst = &S[(((size_t)b*K_ + ii)*K_ + j)*L_ + seg];
            #pragma unroll
            for (int q2 = 0; q2 < 4; ++q2) {
                float4 v;
                v.x = sT[jj][seg + q2*4 + 0];
                v.y = sT[jj][seg + q2*4 + 1];
                v.z = sT[jj][seg + q2*4 + 2];
                v.w = sT[jj][seg + q2*4 + 3];
                *(float4*)&dst[q2*4] = v;
            }
        }
    }
}

// ---------- ctxt v6: v4 structure, but prefetch issued AFTER the barrier ----------
// grid 512 = 16 m-blocks x 8 t-blocks(32) x 2 modes x B; 512 threads, 8 waves.
// Step order: write staged regs -> barrier -> ISSUE next loads -> compute.
// The vmcnt wait for the prefetch now lands at the NEXT step's ds_write (after a
// full compute phase), not at the barrier -> L3 latency hidden under MFMA.
// WAR on buf[t&1]: write(t) is after barrier(t-1), compute(t-2) before it. Safe.
__global__ __launch_bounds__(512, 4) void ctxt_v6(
    const unsigned short* __restrict__ Pt, const float* __restrict__ U,
    const unsigned short* __restrict__ WAb, const unsigned short* __restrict__ WBb,
    const float* __restrict__ lens, float* __restrict__ cacc)
{
    const int bid = blockIdx.x;
    const int m0 = (bid & 15) << 4;
    const int t0 = ((bid >> 4) & 7) << 5;
    const int mode = (bid >> 7) & 1;
    const int b = bid >> 8;
    const unsigned short* __restrict__ Wb = mode ? WBb : WAb;
    const int tid = threadIdx.x;
    const int w = tid >> 6, lane = tid & 63, col = lane & 15, quad = lane >> 4;
    const int dbase = w * 96;

    __shared__ unsigned short sP[2][16][72];   // P t-row tile: 16 m x 64 L, padded
    __shared__ float sU[2][768];               // U[t, 0:768]

    // B fragments for this wave's 96-d slice: 48 VGPRs
    bf16x8 bw[6][2];
    #pragma unroll
    for (int dt = 0; dt < 6; ++dt)
        #pragma unroll
        for (int kc = 0; kc < 2; ++kc)
            bw[dt][kc] = ldb(&Wb[(size_t)(dbase + dt*16 + col)*L_ + kc*32 + quad*8]);

    const bool doP = tid < 128;
    const bool doU = (tid >= 128) && (tid < 320);
    const int prow = (tid & 127) >> 3, pseg = (tid & 7) * 8;   // P stager coords
    const int ucol = (tid - 128) * 4;                          // U stager coords
    size_t pbase, tstep;
    if (mode) { pbase = (((size_t)b*K_ + t0)*K_ + m0 + prow)*L_ + pseg; tstep = (size_t)K_*L_; }
    else      { pbase = (((size_t)b*K_ + m0 + prow)*K_ + t0)*L_ + pseg; tstep = (size_t)L_; }

    ushort8 pv; float4 uv;
    if (doP) pv = *(const ushort8*)&Pt[pbase];
    if (doU) uv = *(const float4*)&U[((size_t)b*K_ + t0)*D_ + ucol];

    f32x4 acc[6] = {};
    for (int t = 0; t < 32; ++t) {
        unsigned short (*bp)[72] = sP[t & 1];
        float* bu = sU[t & 1];
        if (doP) *(ushort8*)&bp[prow][pseg] = pv;
        if (doU) *(float4*)&bu[ucol] = uv;
        __syncthreads();
        // prefetch AFTER the barrier: latency overlaps the compute below
        if (t < 31) {
            if (doP) pv = *(const ushort8*)&Pt[pbase + (size_t)(t + 1)*tstep];
            if (doU) uv = *(const float4*)&U[((size_t)b*K_ + t0 + t + 1)*D_ + ucol];
        }
        bf16x8 a0 = ldb(&bp[col][quad*8]);
        bf16x8 a1 = ldb(&bp[col][32 + quad*8]);
        #pragma unroll
        for (int dt = 0; dt < 6; ++dt) {
            f32x4 g = {0.f, 0.f, 0.f, 0.f};
            g = __builtin_amdgcn_mfma_f32_16x16x32_bf16(a0, bw[dt][0], g, 0, 0, 0);
            g = __builtin_amdgcn_mfma_f32_16x16x32_bf16(a1, bw[dt][1], g, 0, 0, 0);
            const float uu = bu[dbase + dt*16 + col];
            acc[dt] += g * uu;
        }
    }

    const float inv_len = 1.0f / lens[b];
    #pragma unroll
    for (int dt = 0; dt < 6; ++dt)
        #pragma unroll
        for (int r = 0; r < 4; ++r) {
            const int m = m0 + quad*4 + r;
            atomicAdd(&cacc[((size_t)(b*K_) + m)*D_ + dbase + dt*16 + col],
                      acc[dt][r] * inv_len);
        }
}

// ---------- gate via MFMA (1 wave / 16x64 tile), cconv fused ----------
__global__ __launch_bounds__(64) void gate_mfma(
    const unsigned short* __restrict__ Ub, const unsigned short* __restrict__ gwb,
    const float* __restrict__ gb,
    const float* __restrict__ Ucur, const float* __restrict__ Cc,
    float* __restrict__ Unext, unsigned short* __restrict__ Ubnext)
{
    const int r0 = blockIdx.x * 16, n0 = blockIdx.y * 64;
    const int lane = threadIdx.x;
    const int col = lane & 15, quad = lane >> 4;
    const unsigned short* arow_u = &Ub[(size_t)(r0 + col)*D_ + quad*8];
    const float* arow_c = &Cc[(size_t)(r0 + col)*D_ + quad*8];
    f32x4 acc[4] = {};
    #pragma unroll 4
    for (int kc = 0; kc < D_; kc += 32) {
        bf16x8 a = ldb(arow_u + kc);
        #pragma unroll
        for (int nt = 0; nt < 4; ++nt) {
            bf16x8 bb = ldb(&gwb[(size_t)(n0 + nt*16 + col)*(2*D_) + kc + quad*8]);
            acc[nt] = __builtin_amdgcn_mfma_f32_16x16x32_bf16(a, bb, acc[nt], 0, 0, 0);
        }
    }
    #pragma unroll 4
    for (int kc = 0; kc < D_; kc += 32) {
        bf16x8 a = cvt8(arow_c + kc);
        #pragma unroll
        for (int nt = 0; nt < 4; ++nt) {
            bf16x8 bb = ldb(&gwb[(size_t)(n0 + nt*16 + col)*(2*D_) + D_ + kc + quad*8]);
            acc[nt] = __builtin_amdgcn_mfma_f32_16x16x32_bf16(a, bb, acc[nt], 0, 0, 0);
        }
    }
    #pragma unroll
    for (int nt = 0; nt < 4; ++nt) {
        const int n = n0 + nt*16 + col;
        const float gbv = gb[n];
        #pragma unroll
        for (int r = 0; r < 4; ++r) {
            const size_t idx = (size_t)(r0 + quad*4 + r)*D_ + n;
            const float gg = sigm(acc[nt][r] + gbv);
            const float o = gg * Ucur[idx] + (1.f - gg) * Cc[idx];
            Unext[idx] = o;
            Ubnext[idx] = f2b(o);
        }
    }
}

// ---------- scatter updated rows into new_all ----------
__global__ __launch_bounds__(256) void scatter_kernel(
    const float* __restrict__ upd, const int* __restrict__ prune,
    const float* __restrict__ lens, float* __restrict__ out_all)
{
    const int blk = blockIdx.x;
    const int b = blk / K_, k = blk % K_;
    if ((float)k < lens[b]) {
        const int pi = prune[b*K_ + k];
        const int tid = threadIdx.x;
        if (tid < D_/4) {
            float4 v = *(const float4*)&upd[((size_t)b*K_ + k)*D_ + tid*4];
            *(float4*)&out_all[((size_t)b*N_ + pi)*D_ + tid*4] = v;
        }
    }
}

extern "C" void kernel_launch(void* const* d_in, const int* in_sizes, int n_in,
                              void* d_out, int out_size, void* d_ws, size_t ws_size,
                              hipStream_t stream) {
    (void)in_sizes; (void)n_in; (void)out_size; (void)ws_size;
    const float* all_span_vecs = (const float*)d_in[0];
    const float* span_vecs     = (const float*)d_in[1];
    const int*   span_begin    = (const int*)d_in[2];
    const int*   span_end      = (const int*)d_in[3];
    const float* mask          = (const float*)d_in[4];
    const float* lens          = (const float*)d_in[5];
    const int*   prune         = (const int*)d_in[6];
    const float* lw  = (const float*)d_in[7];
    const float* lb  = (const float*)d_in[8];
    const float* rw  = (const float*)d_in[9];
    const float* rb  = (const float*)d_in[10];
    const float* dist_emb = (const float*)d_in[11];
    const float* out_w    = (const float*)d_in[12];
    const float* out_b    = (const float*)d_in[13];
    const float* A_w = (const float*)d_in[14];
    const float* B_w = (const float*)d_in[15];
    const float* gw  = (const float*)d_in[16];
    const float* gb  = (const float*)d_in[17];

    float* out_all = (float*)d_out;
    float* out_upd = out_all + (size_t)B_*N_*D_;
    float* out_sc  = out_upd + (size_t)BK_*D_;

    float* ws     = (float*)d_ws;
    float* leftb  = ws;                            // BK*H fp32
    float* rightf = leftb + (size_t)BK_*H_;        // BK*H fp32 (right proj)
    float* U0     = rightf + (size_t)BK_*H_;       // BK*D
    float* U1     = U0 + (size_t)BK_*D_;           // BK*D
    float* cbuf   = U1 + (size_t)BK_*D_;           // BK*D
    unsigned short* WAb = (unsigned short*)(cbuf + (size_t)BK_*D_);
    unsigned short* WBb = WAb + (size_t)D_*L_;
    unsigned short* lwb = WBb + (size_t)D_*L_;
    unsigned short* rwb = lwb + (size_t)H_*D_;
    unsigned short* owb = rwb + (size_t)H_*D_;
    unsigned short* gwb = owb + (size_t)L_*H_;
    unsigned short* deb = gwb + (size_t)D_*2*D_;   // 64*H bf16
    unsigned short* Ub0 = deb + (size_t)64*H_;
    unsigned short* Ub1 = Ub0 + (size_t)BK_*D_;
    unsigned short* Pt  = Ub1 + (size_t)BK_*D_;    // B*K*K*L bf16

    hipMemcpyAsync(out_all, all_span_vecs, sizeof(float)*(size_t)B_*N_*D_,
                   hipMemcpyDeviceToDevice, stream);

    dim3 blk256(256), blk64(64), blk512(512);
    conv_all<<<dim3(2048), blk256, 0, stream>>>(lw, rw, out_w, gw, A_w, B_w, span_vecs, dist_emb,
                                                lwb, rwb, owb, gwb, WAb, WBb, Ub0, deb);
    lr_mfma<<<dim3(BK_/16, H_/64, 2), blk64, 0, stream>>>(Ub0, lwb, lb, rwb, rb, leftb, rightf);
    scores_v9<<<dim3(K_/64, K_/8, B_), blk256, 0, stream>>>(leftb, rightf, span_begin, span_end,
                                                            deb, owb, out_b, mask,
                                                            out_sc, Pt, 1);
    const float* Ucur = span_vecs;
    const unsigned short* Ubcur = Ub0;
    float* nexts[3] = {U0, U1, out_upd};
    unsigned short* nextsUb[3] = {Ub1, Ub0, Ub1};
    for (int it = 0; it < 3; ++it) {
        hipMemsetAsync(cbuf, 0, sizeof(float)*(size_t)BK_*D_, stream);
        ctxt_v6<<<dim3(512), blk512, 0, stream>>>(Pt, Ucur, WAb, WBb, lens, cbuf);
        gate_mfma<<<dim3(BK_/16, D_/64), blk64, 0, stream>>>(Ubcur, gwb, gb,
                                                             Ucur, cbuf, nexts[it], nextsUb[it]);
        Ucur = nexts[it];
        Ubcur = nextsUb[it];
        lr_mfma<<<dim3(BK_/16, H_/64, 2), blk64, 0, stream>>>(Ubcur, lwb, lb, rwb, rb, leftb, rightf);
        scores_v9<<<dim3(K_/64, K_/8, B_), blk256, 0, stream>>>(leftb, rightf, span_begin, span_end,
                                                                deb, owb, out_b, mask,
                                                                out_sc, Pt, it == 2 ? 0 : 1);
    }
    scatter_kernel<<<dim3(BK_), blk256, 0, stream>>>(out_upd, prune, lens, out_all);
}

// Round 7
// 428.771 us; speedup vs baseline: 3.5742x; 1.0247x over previous
//
#include <hip/hip_runtime.h>

#define B_ 2
#define N_ 2048
#define K_ 256
#define D_ 768
#define H_ 256
#define L_ 64
#define BK_ (B_*K_)

typedef __attribute__((ext_vector_type(8))) __bf16 bf16x8;
typedef __attribute__((ext_vector_type(8))) unsigned short ushort8;
typedef __attribute__((ext_vector_type(4))) unsigned short ushort4v;
typedef __attribute__((ext_vector_type(4))) float f32x4;

__device__ __forceinline__ float sigm(float x) { return 1.0f / (1.0f + __expf(-x)); }

// round-to-nearest-even fp32 -> bf16 (bit-twiddle; cold paths)
__device__ __forceinline__ unsigned short f2b(float f) {
    union { float f; unsigned int u; } v; v.f = f;
    unsigned int u = v.u;
    return (unsigned short)((u + 0x7FFFu + ((u >> 16) & 1u)) >> 16);
}
// hardware cvt (compiler emits v_cvt_pk_bf16_f32 for pairs; hot paths)
__device__ __forceinline__ unsigned short f2bc(float f) {
    __bf16 h = (__bf16)f;
    return __builtin_bit_cast(unsigned short, h);
}
__device__ __forceinline__ float b2f(unsigned short us) {
    union { unsigned int u; float f; } v; v.u = ((unsigned int)us) << 16;
    return v.f;
}
__device__ __forceinline__ bf16x8 ldb(const unsigned short* p) {
    ushort8 v = *(const ushort8*)p;
    return __builtin_bit_cast(bf16x8, v);
}

// ---------- one-shot fp32->bf16 conversion of all static operands (incl. dist_emb) --
__global__ __launch_bounds__(256) void conv_all(
    const float* __restrict__ lw, const float* __restrict__ rw,
    const float* __restrict__ ow, const float* __restrict__ gw,
    const float* __restrict__ aw, const float* __restrict__ bw,
    const float* __restrict__ sv, const float* __restrict__ de,
    unsigned short* __restrict__ lwb, unsigned short* __restrict__ rwb,
    unsigned short* __restrict__ owb, unsigned short* __restrict__ gwb,
    unsigned short* __restrict__ wab, unsigned short* __restrict__ wbb,
    unsigned short* __restrict__ ub, unsigned short* __restrict__ deb)
{
    int i4 = (blockIdx.x * 256 + threadIdx.x) * 4;
    const float* src; unsigned short* dst; int off;
    if      (i4 <  196608) { src = lw; dst = lwb; off = 0; }
    else if (i4 <  393216) { src = rw; dst = rwb; off = 196608; }
    else if (i4 <  409600) { src = ow; dst = owb; off = 393216; }
    else if (i4 < 1589248) { src = gw; dst = gwb; off = 409600; }
    else if (i4 < 1638400) { src = aw; dst = wab; off = 1589248; }
    else if (i4 < 1687552) { src = bw; dst = wbb; off = 1638400; }
    else if (i4 < 2080768) { src = sv; dst = ub;  off = 1687552; }
    else if (i4 < 2097152) { src = de; dst = deb; off = 2080768; }
    else return;
    int j = i4 - off;
    float4 v = *(const float4*)&src[j];
    ushort4v p; p.x = f2b(v.x); p.y = f2b(v.y); p.z = f2b(v.z); p.w = f2b(v.w);
    *(ushort4v*)&dst[j] = p;
}

// ---------- cbuf fp32 -> bf16 (so gate's c-side A is a plain ldb) ----------
__global__ __launch_bounds__(256) void conv_c(
    const float* __restrict__ c, unsigned short* __restrict__ cb)
{
    int i = (blockIdx.x * 256 + threadIdx.x) * 4;
    float4 v = *(const float4*)&c[i];
    ushort4v p; p.x = f2b(v.x); p.y = f2b(v.y); p.z = f2b(v.z); p.w = f2b(v.w);
    *(ushort4v*)&cb[i] = p;
}

// ---------- left/right projections: 16x16 tile per wave, 4x more TLP ----------
// grid (BK/16=32, H/16=16, 2) = 1024 single-wave blocks.
__global__ __launch_bounds__(64) void lr_mfma2(
    const unsigned short* __restrict__ Ub,
    const unsigned short* __restrict__ lwb, const float* __restrict__ lb,
    const unsigned short* __restrict__ rwb, const float* __restrict__ rb,
    float* __restrict__ outL, float* __restrict__ outR)
{
    const int side = blockIdx.z;
    const unsigned short* __restrict__ W = side ? rwb : lwb;
    const float* __restrict__ bias = side ? rb : lb;
    float* __restrict__ outp = side ? outR : outL;
    const int r0 = blockIdx.x * 16, n0 = blockIdx.y * 16;
    const int lane = threadIdx.x;
    const int col = lane & 15, quad = lane >> 4;
    const unsigned short* arow = &Ub[(size_t)(r0 + col)*D_ + quad*8];
    const unsigned short* brow = &W[(size_t)(n0 + col)*D_ + quad*8];
    f32x4 acc = {};
    #pragma unroll
    for (int kc = 0; kc < D_; kc += 32) {
        bf16x8 a = ldb(arow + kc);
        bf16x8 bb = ldb(brow + kc);
        acc = __builtin_amdgcn_mfma_f32_16x16x32_bf16(a, bb, acc, 0, 0, 0);
    }
    const int n = n0 + col;
    const float bv = bias[n];
    #pragma unroll
    for (int r = 0; r < 4; ++r)
        outp[(size_t)(r0 + quad*4 + r)*H_ + n] = acc[r] + bv;
}

// ---------- scores v9: LDS-resident dist-emb table (bf16, padded), k-outer ----------
// grid (K/64=4, K/8=32, B=2) = 256 blocks, 256 threads, 2 blocks/CU.
__global__ __launch_bounds__(256, 2) void scores_v9(
    const float* __restrict__ leftb, const float* __restrict__ rightb,
    const int* __restrict__ span_begin, const int* __restrict__ span_end,
    const unsigned short* __restrict__ deb, const unsigned short* __restrict__ owb,
    const float* __restrict__ out_b, const float* __restrict__ mask,
    float* __restrict__ S, unsigned short* __restrict__ Pt, int writeP)
{
    const int j0 = blockIdx.x * 64;
    const int i0 = blockIdx.y * 8;
    const int b  = blockIdx.z;
    const int tid = threadIdx.x;
    const int w = tid >> 6, lane = tid & 63, col = lane & 15, quad = lane >> 4;
    const int jrow = w*16 + col;

    __shared__ unsigned short sDe[64][272];  // full dist-emb table bf16, padded rows
    __shared__ float sL[8][256];             // left i-tile fp32
    __shared__ float sT[64][68];             // per-i transpose buffer
    __shared__ float sMask[8][64];
    __shared__ int   sBkt[8][64];

    // stage dist-emb table: 2048 ushort8 chunks
    #pragma unroll
    for (int q = 0; q < 8; ++q) {
        int c = tid + q*256;
        int row = c >> 5, seg = (c & 31) * 8;
        *(ushort8*)&sDe[row][seg] = *(const ushort8*)&deb[row*H_ + seg];
    }
    // buckets + mask (512 pairs)
    #pragma unroll
    for (int q = 0; q < 2; ++q) {
        int p = tid + q*256;
        int ii = p >> 6, jj = p & 63;
        int d = span_begin[b*K_ + j0 + jj] - span_end[b*K_ + i0 + ii];
        if (d < 0) d = -d;
        sBkt[ii][jj] = d > 63 ? 63 : d;
        sMask[ii][jj] = mask[(size_t)(b*K_ + i0 + ii)*K_ + j0 + jj];
    }
    // left tile: 512 float4s
    #pragma unroll
    for (int q = 0; q < 2; ++q) {
        int f = tid + q*256;
        int row = f >> 6, c4 = (f & 63) * 4;
        *(float4*)&sL[row][c4] = *(const float4*)&leftb[(size_t)(b*K_ + i0 + row)*H_ + c4];
    }
    __syncthreads();

    const unsigned short* sDeF = &sDe[0][0];
    int deoff[8];
    #pragma unroll
    for (int i = 0; i < 8; ++i) deoff[i] = sBkt[i][jrow] * 272;

    const float* rrow = &rightb[(size_t)(b*K_ + j0 + jrow)*H_ + quad*8];

    f32x4 acc[8][4] = {};
    #pragma unroll
    for (int k = 0; k < 8; ++k) {
        const float4 r0 = *(const float4*)&rrow[k*32];
        const float4 r1 = *(const float4*)&rrow[k*32 + 4];
        bf16x8 bbk[4];
        #pragma unroll
        for (int lt = 0; lt < 4; ++lt)
            bbk[lt] = ldb(&owb[(size_t)(lt*16 + col)*H_ + k*32 + quad*8]);
        #pragma unroll
        for (int i = 0; i < 8; ++i) {
            const ushort8 dv = *(const ushort8*)&sDeF[deoff[i] + k*32 + quad*8];
            const float* lr = &sL[i][k*32 + quad*8];
            const float4 l0 = *(const float4*)lr;
            const float4 l1 = *(const float4*)(lr + 4);
            bf16x8 a;
            a[0] = (__bf16)fmaxf(0.f, l0.x + r0.x + b2f(dv[0]));
            a[1] = (__bf16)fmaxf(0.f, l0.y + r0.y + b2f(dv[1]));
            a[2] = (__bf16)fmaxf(0.f, l0.z + r0.z + b2f(dv[2]));
            a[3] = (__bf16)fmaxf(0.f, l0.w + r0.w + b2f(dv[3]));
            a[4] = (__bf16)fmaxf(0.f, l1.x + r1.x + b2f(dv[4]));
            a[5] = (__bf16)fmaxf(0.f, l1.y + r1.y + b2f(dv[5]));
            a[6] = (__bf16)fmaxf(0.f, l1.z + r1.z + b2f(dv[6]));
            a[7] = (__bf16)fmaxf(0.f, l1.w + r1.w + b2f(dv[7]));
            #pragma unroll
            for (int lt = 0; lt < 4; ++lt)
                acc[i][lt] = __builtin_amdgcn_mfma_f32_16x16x32_bf16(a, bbk[lt], acc[i][lt], 0, 0, 0);
        }
    }

    float ob[4];
    #pragma unroll
    for (int lt = 0; lt < 4; ++lt) ob[lt] = out_b[lt*16 + col];

    #pragma unroll                      // keep acc[i] statically indexed (rule #20)
    for (int i = 0; i < 8; ++i) {
        __syncthreads();   // prior i's sT reads done
        #pragma unroll
        for (int lt = 0; lt < 4; ++lt)
            #pragma unroll
            for (int r = 0; r < 4; ++r)
                sT[w*16 + quad*4 + r][lt*16 + col] = acc[i][lt][r] + ob[lt];
        __syncthreads();
        const int jj = tid >> 2, seg = (tid & 3) * 16;
        const int j = j0 + jj, ii = i0 + i;
        if (writeP) {
            const float msk = sMask[i][jj];
            ushort8 o0, o1;
            #pragma unroll
            for (int e = 0; e < 8; ++e) {
                o0[e] = f2bc(sigm(sT[jj][seg + e]) * msk);
                o1[e] = f2bc(sigm(sT[jj][seg + 8 + e]) * msk);
            }
            unsigned short* dst = &Pt[(((size_t)b*K_ + j)*K_ + ii)*L_ + seg];
            *(ushort8*)&dst[0] = o0;
            *(ushort8*)&dst[8] = o1;
        } else {
            float* dst = &S[(((size_t)b*K_ + ii)*K_ + j)*L_ + seg];
            #pragma unroll
            for (int q2 = 0; q2 < 4; ++q2) {
                float4 v;
                v.x = sT[jj][seg + q2*4 + 0];
                v.y = sT[jj][seg + q2*4 + 1];
                v.z = sT[jj][seg + q2*4 + 2];
                v.w = sT[jj][seg + q2*4 + 3];
                *(float4*)&dst[q2*4] = v;
            }
        }
    }
}

// ---------- ctxt v7: v6 + 2-deep register prefetch (load t+2 at step t) ----------
// grid 512 = 16 m-blocks x 8 t-blocks(32) x 2 modes x B; 512 threads, 8 waves.
// write(pvX) -> barrier -> issue load(t+2) -> compute. The ds_write of load(t+2)'s
// data happens at step t+2 -> two compute phases of slack (counted vmcnt wait).
__global__ __launch_bounds__(512, 4) void ctxt_v7(
    const unsigned short* __restrict__ Pt, const float* __restrict__ U,
    const unsigned short* __restrict__ WAb, const unsigned short* __restrict__ WBb,
    const float* __restrict__ lens, float* __restrict__ cacc)
{
    const int bid = blockIdx.x;
    const int m0 = (bid & 15) << 4;
    const int t0 = ((bid >> 4) & 7) << 5;
    const int mode = (bid >> 7) & 1;
    const int b = bid >> 8;
    const unsigned short* __restrict__ Wb = mode ? WBb : WAb;
    const int tid = threadIdx.x;
    const int w = tid >> 6, lane = tid & 63, col = lane & 15, quad = lane >> 4;
    const int dbase = w * 96;

    __shared__ unsigned short sP[2][16][72];   // P t-row tile: 16 m x 64 L, padded
    __shared__ float sU[2][768];               // U[t, 0:768]

    bf16x8 bw[6][2];
    #pragma unroll
    for (int dt = 0; dt < 6; ++dt)
        #pragma unroll
        for (int kc = 0; kc < 2; ++kc)
            bw[dt][kc] = ldb(&Wb[(size_t)(dbase + dt*16 + col)*L_ + kc*32 + quad*8]);

    const bool doP = tid < 128;
    const bool doU = (tid >= 128) && (tid < 320);
    const int prow = (tid & 127) >> 3, pseg = (tid & 7) * 8;
    const int ucol = (tid - 128) * 4;
    size_t pbase, tstep;
    if (mode) { pbase = (((size_t)b*K_ + t0)*K_ + m0 + prow)*L_ + pseg; tstep = (size_t)K_*L_; }
    else      { pbase = (((size_t)b*K_ + m0 + prow)*K_ + t0)*L_ + pseg; tstep = (size_t)L_; }

    ushort8 pvA, pvB; float4 uvA, uvB;
    if (doP) { pvA = *(const ushort8*)&Pt[pbase];
               pvB = *(const ushort8*)&Pt[pbase + tstep]; }
    if (doU) { uvA = *(const float4*)&U[((size_t)b*K_ + t0)*D_ + ucol];
               uvB = *(const float4*)&U[((size_t)b*K_ + t0 + 1)*D_ + ucol]; }

    f32x4 acc[6] = {};

    #define CTXT_COMPUTE(BUFI)                                                    \
    {                                                                             \
        bf16x8 a0 = ldb(&sP[BUFI][col][quad*8]);                                  \
        bf16x8 a1 = ldb(&sP[BUFI][col][32 + quad*8]);                             \
        _Pragma("unroll")                                                         \
        for (int dt = 0; dt < 6; ++dt) {                                          \
            f32x4 g = {0.f, 0.f, 0.f, 0.f};                                       \
            g = __builtin_amdgcn_mfma_f32_16x16x32_bf16(a0, bw[dt][0], g, 0, 0, 0); \
            g = __builtin_amdgcn_mfma_f32_16x16x32_bf16(a1, bw[dt][1], g, 0, 0, 0); \
            const float uu = sU[BUFI][dbase + dt*16 + col];                       \
            acc[dt] += g * uu;                                                    \
        }                                                                         \
    }

    for (int t = 0; t < 32; t += 2) {
        // even phase: buffer 0
        if (doP) *(ushort8*)&sP[0][prow][pseg] = pvA;
        if (doU) *(float4*)&sU[0][ucol] = uvA;
        __syncthreads();
        if (t + 2 < 32) {
            if (doP) pvA = *(const ushort8*)&Pt[pbase + (size_t)(t + 2)*tstep];
            if (doU) uvA = *(const float4*)&U[((size_t)b*K_ + t0 + t + 2)*D_ + ucol];
        }
        CTXT_COMPUTE(0)
        // odd phase: buffer 1
        if (doP) *(ushort8*)&sP[1][prow][pseg] = pvB;
        if (doU) *(float4*)&sU[1][ucol] = uvB;
        __syncthreads();
        if (t + 3 < 32) {
            if (doP) pvB = *(const ushort8*)&Pt[pbase + (size_t)(t + 3)*tstep];
            if (doU) uvB = *(const float4*)&U[((size_t)b*K_ + t0 + t + 3)*D_ + ucol];
        }
        CTXT_COMPUTE(1)
    }
    #undef CTXT_COMPUTE

    const float inv_len = 1.0f / lens[b];
    #pragma unroll
    for (int dt = 0; dt < 6; ++dt)
        #pragma unroll
        for (int r = 0; r < 4; ++r) {
            const int m = m0 + quad*4 + r;
            atomicAdd(&cacc[((size_t)(b*K_) + m)*D_ + dbase + dt*16 + col],
                      acc[dt][r] * inv_len);
        }
}

// ---------- gate: 16x16 tile per wave, bf16 c input, 4x more TLP ----------
// grid (BK/16=32, D/16=48) = 1536 single-wave blocks.
__global__ __launch_bounds__(64) void gate_mfma2(
    const unsigned short* __restrict__ Ub, const unsigned short* __restrict__ cb,
    const unsigned short* __restrict__ gwb, const float* __restrict__ gb,
    const float* __restrict__ Ucur, const float* __restrict__ Cc,
    float* __restrict__ Unext, unsigned short* __restrict__ Ubnext)
{
    const int r0 = blockIdx.x * 16, n0 = blockIdx.y * 16;
    const int lane = threadIdx.x;
    const int col = lane & 15, quad = lane >> 4;
    const unsigned short* arow_u = &Ub[(size_t)(r0 + col)*D_ + quad*8];
    const unsigned short* arow_c = &cb[(size_t)(r0 + col)*D_ + quad*8];
    const unsigned short* brow   = &gwb[(size_t)(n0 + col)*(2*D_) + quad*8];
    f32x4 acc = {};
    #pragma unroll
    for (int kc = 0; kc < D_; kc += 32) {
        bf16x8 a = ldb(arow_u + kc);
        bf16x8 bb = ldb(brow + kc);
        acc = __builtin_amdgcn_mfma_f32_16x16x32_bf16(a, bb, acc, 0, 0, 0);
    }
    #pragma unroll
    for (int kc = 0; kc < D_; kc += 32) {
        bf16x8 a = ldb(arow_c + kc);
        bf16x8 bb = ldb(brow + D_ + kc);
        acc = __builtin_amdgcn_mfma_f32_16x16x32_bf16(a, bb, acc, 0, 0, 0);
    }
    const int n = n0 + col;
    const float gbv = gb[n];
    #pragma unroll
    for (int r = 0; r < 4; ++r) {
        const size_t idx = (size_t)(r0 + quad*4 + r)*D_ + n;
        const float gg = sigm(acc[r] + gbv);
        const float o = gg * Ucur[idx] + (1.f - gg) * Cc[idx];
        Unext[idx] = o;
        Ubnext[idx] = f2b(o);
    }
}

// ---------- scatter updated rows into new_all ----------
__global__ __launch_bounds__(256) void scatter_kernel(
    const float* __restrict__ upd, const int* __restrict__ prune,
    const float* __restrict__ lens, float* __restrict__ out_all)
{
    const int blk = blockIdx.x;
    const int b = blk / K_, k = blk % K_;
    if ((float)k < lens[b]) {
        const int pi = prune[b*K_ + k];
        const int tid = threadIdx.x;
        if (tid < D_/4) {
            float4 v = *(const float4*)&upd[((size_t)b*K_ + k)*D_ + tid*4];
            *(float4*)&out_all[((size_t)b*N_ + pi)*D_ + tid*4] = v;
        }
    }
}

extern "C" void kernel_launch(void* const* d_in, const int* in_sizes, int n_in,
                              void* d_out, int out_size, void* d_ws, size_t ws_size,
                              hipStream_t stream) {
    (void)in_sizes; (void)n_in; (void)out_size; (void)ws_size;
    const float* all_span_vecs = (const float*)d_in[0];
    const float* span_vecs     = (const float*)d_in[1];
    const int*   span_begin    = (const int*)d_in[2];
    const int*   span_end      = (const int*)d_in[3];
    const float* mask          = (const float*)d_in[4];
    const float* lens          = (const float*)d_in[5];
    const int*   prune         = (const int*)d_in[6];
    const float* lw  = (const float*)d_in[7];
    const float* lb  = (const float*)d_in[8];
    const float* rw  = (const float*)d_in[9];
    const float* rb  = (const float*)d_in[10];
    const float* dist_emb = (const float*)d_in[11];
    const float* out_w    = (const float*)d_in[12];
    const float* out_b    = (const float*)d_in[13];
    const float* A_w = (const float*)d_in[14];
    const float* B_w = (const float*)d_in[15];
    const float* gw  = (const float*)d_in[16];
    const float* gb  = (const float*)d_in[17];

    float* out_all = (float*)d_out;
    float* out_upd = out_all + (size_t)B_*N_*D_;
    float* out_sc  = out_upd + (size_t)BK_*D_;

    float* ws     = (float*)d_ws;
    float* leftb  = ws;                            // BK*H fp32
    float* rightf = leftb + (size_t)BK_*H_;        // BK*H fp32 (right proj)
    float* U0     = rightf + (size_t)BK_*H_;       // BK*D
    float* U1     = U0 + (size_t)BK_*D_;           // BK*D
    float* cbuf   = U1 + (size_t)BK_*D_;           // BK*D
    unsigned short* WAb = (unsigned short*)(cbuf + (size_t)BK_*D_);
    unsigned short* WBb = WAb + (size_t)D_*L_;
    unsigned short* lwb = WBb + (size_t)D_*L_;
    unsigned short* rwb = lwb + (size_t)H_*D_;
    unsigned short* owb = rwb + (size_t)H_*D_;
    unsigned short* gwb = owb + (size_t)L_*H_;
    unsigned short* deb = gwb + (size_t)D_*2*D_;   // 64*H bf16
    unsigned short* Ub0 = deb + (size_t)64*H_;
    unsigned short* Ub1 = Ub0 + (size_t)BK_*D_;
    unsigned short* cb  = Ub1 + (size_t)BK_*D_;    // BK*D bf16 (c context)
    unsigned short* Pt  = cb + (size_t)BK_*D_;     // B*K*K*L bf16

    hipMemcpyAsync(out_all, all_span_vecs, sizeof(float)*(size_t)B_*N_*D_,
                   hipMemcpyDeviceToDevice, stream);

    dim3 blk256(256), blk64(64), blk512(512);
    conv_all<<<dim3(2048), blk256, 0, stream>>>(lw, rw, out_w, gw, A_w, B_w, span_vecs, dist_emb,
                                                lwb, rwb, owb, gwb, WAb, WBb, Ub0, deb);
    lr_mfma2<<<dim3(BK_/16, H_/16, 2), blk64, 0, stream>>>(Ub0, lwb, lb, rwb, rb, leftb, rightf);
    scores_v9<<<dim3(K_/64, K_/8, B_), blk256, 0, stream>>>(leftb, rightf, span_begin, span_end,
                                                            deb, owb, out_b, mask,
                                                            out_sc, Pt, 1);
    const float* Ucur = span_vecs;
    const unsigned short* Ubcur = Ub0;
    float* nexts[3] = {U0, U1, out_upd};
    unsigned short* nextsUb[3] = {Ub1, Ub0, Ub1};
    for (int it = 0; it < 3; ++it) {
        hipMemsetAsync(cbuf, 0, sizeof(float)*(size_t)BK_*D_, stream);
        ctxt_v7<<<dim3(512), blk512, 0, stream>>>(Pt, Ucur, WAb, WBb, lens, cbuf);
        conv_c<<<dim3(BK_*D_/1024), blk256, 0, stream>>>(cbuf, cb);
        gate_mfma2<<<dim3(BK_/16, D_/16), blk64, 0, stream>>>(Ubcur, cb, gwb, gb,
                                                              Ucur, cbuf, nexts[it], nextsUb[it]);
        Ucur = nexts[it];
        Ubcur = nextsUb[it];
        lr_mfma2<<<dim3(BK_/16, H_/16, 2), blk64, 0, stream>>>(Ubcur, lwb, lb, rwb, rb, leftb, rightf);
        scores_v9<<<dim3(K_/64, K_/8, B_), blk256, 0, stream>>>(leftb, rightf, span_begin, span_end,
                                                                deb, owb, out_b, mask,
                                                                out_sc, Pt, it == 2 ? 0 : 1);
    }
    scatter_kernel<<<dim3(BK_), blk256, 0, stream>>>(out_upd, prune, lens, out_all);
}